// Round 18
// baseline (216.408 us; speedup 1.0000x reference)
//
#include <hip/hip_runtime.h>
#include <math.h>

#define NN 100000
#define NE 1600000
#define NETOT (NE + NN)
#define FIN 128
#define H1N 8
#define D1 64
#define NC 40
#define LNT 64                        // nodes per tile in lin1
#define LOG2E 1.44269504088896f

#define BSH 9                         // 512 dst nodes per bucket
#define BNODES 512
#define NBUC ((NN + BNODES - 1) / BNODES)   // 196
#define EPB 4096                      // edges per passA block
#define NBLKA ((NE + EPB - 1) / EPB)  // 391
#define BCAP 9216                     // per-bucket edge capacity (mean 8192, +11 sigma)
#define LB ((NN + LNT - 1) / LNT)     // 1563

__device__ __forceinline__ float leakyf(float x) { return x >= 0.0f ? x : 0.2f * x; }
__device__ __forceinline__ float eluf(float x)   { return x > 0.0f ? x : expm1f(x); }
__device__ __forceinline__ float exp2fast(float x) { return __builtin_amdgcn_exp2f(x); }

// bf16 helpers
__device__ __forceinline__ unsigned short f2bf(float f) {
  unsigned u = __float_as_uint(f);
  u += 0x7fffu + ((u >> 16) & 1u);
  return (unsigned short)(u >> 16);
}
__device__ __forceinline__ float bflo(unsigned u) { return __uint_as_float(u << 16); }
__device__ __forceinline__ float bfhi(unsigned u) { return __uint_as_float(u & 0xffff0000u); }

// ---- detect edge dtype + zero bucket counters ----------------------------
__global__ void k_detect(const long long* __restrict__ ei, int* __restrict__ flag,
                         int* __restrict__ bcnt) {
  int t = threadIdx.x;
  if (t < NBUC) bcnt[t] = 0;
  if (t == 0) {
    int is64 = 1;
    for (int i = 0; i < 16; ++i) {
      long long v = ei[i];
      if (v < 0 || v >= NN) is64 = 0;
    }
    *flag = is64;
  }
}

// ---- fused: blocks [0,NBLKA) = passA bucket-sort; rest = lin1 GEMM -------
#define XS1(node, k) xs[(node) * FIN + ((k) ^ ((node) & 31))]
__global__ __launch_bounds__(512) void k_fusedA(
    const void* __restrict__ ei, const int* __restrict__ flag,
    unsigned int* __restrict__ subbuf, int* __restrict__ bcnt,
    const float* __restrict__ x, const float* __restrict__ W,
    const float* __restrict__ aw_s, const float* __restrict__ aw_d,
    unsigned short* __restrict__ h, float* __restrict__ als,
    float* __restrict__ ald) {
  __shared__ __align__(16) char smem[65536];
  int t = threadIdx.x;
  if (blockIdx.x < NBLKA) {
    // ---------------- passA: block-local LDS counting sort ----------------
    unsigned int*   pay    = (unsigned int*)smem;            // 16KB
    unsigned int*   spay   = pay + EPB;                      // 16KB
    unsigned short* bk     = (unsigned short*)(spay + EPB);  // 8KB
    unsigned short* sbk    = bk + EPB;                       // 8KB
    int*            hist   = (int*)(sbk + EPB);              // 1KB
    int*            lstart = hist + 256;                     // 1KB
    int*            cur    = lstart + 256;                   // 1KB
    int*            gbase  = cur + 256;                      // 1KB
    int e0 = blockIdx.x * EPB;
    int cnt = min(EPB, NE - e0);
    if (t < 256) hist[t] = 0;
    __syncthreads();
    bool f64 = (*flag) != 0;
    for (int i = t; i < cnt; i += 512) {
      int s, d;
      if (f64) {
        const long long* p = (const long long*)ei;
        s = (int)p[e0 + i]; d = (int)p[NE + e0 + i];
      } else {
        const int* p = (const int*)ei;
        s = p[e0 + i]; d = p[NE + e0 + i];
      }
      int b = d >> BSH;
      pay[i] = ((unsigned)s << BSH) | (unsigned)(d & (BNODES - 1));
      bk[i] = (unsigned short)b;
      atomicAdd(&hist[b], 1);
    }
    __syncthreads();
    int v = 0;
    if (t < 256) { v = hist[t]; lstart[t] = v; }
    __syncthreads();
    for (int st = 1; st < 256; st <<= 1) {
      int xv = (t < 256 && t >= st) ? lstart[t - st] : 0;
      __syncthreads();
      if (t < 256) lstart[t] += xv;
      __syncthreads();
    }
    int excl = 0;
    if (t < 256) excl = lstart[t] - v;
    __syncthreads();
    if (t < 256) {
      lstart[t] = excl;
      cur[t] = excl;
      gbase[t] = (v > 0) ? atomicAdd(&bcnt[t], v) : 0;
    }
    __syncthreads();
    for (int i = t; i < cnt; i += 512) {
      int b = bk[i];
      int pos = atomicAdd(&cur[b], 1);
      spay[pos] = pay[i];
      sbk[pos] = (unsigned short)b;
    }
    __syncthreads();
    for (int i = t; i < cnt; i += 512) {
      int b = sbk[i];
      int o = gbase[b] + (i - lstart[b]);
      if (o < BCAP) subbuf[(size_t)b * BCAP + o] = spay[i];
    }
  } else {
    // ---------------- lin1: LDS-tiled GEMM, 1 node x 8 cols / thread ------
    float* ws = (float*)smem;            // 32KB [128][64]
    float* xs = ws + FIN * D1;           // 32KB [64][128] swizzled
    int base = (blockIdx.x - NBLKA) * LNT;
    for (int i = t; i < FIN * D1; i += 512) ws[i] = W[i];
    for (int i = t; i < LNT * FIN; i += 512) {
      int node = i >> 7, k = i & 127;
      int gn = base + node;
      if (gn >= NN) gn = NN - 1;
      XS1(node, k) = x[(size_t)gn * FIN + k];
    }
    __syncthreads();
    int g = t & 7, nl = t >> 3;          // head g, node nl in 0..63
    float acc[8] = {0, 0, 0, 0, 0, 0, 0, 0};
    #pragma unroll 4
    for (int k = 0; k < FIN; ++k) {
      float x0 = XS1(nl, k);
      const float4* wr = (const float4*)&ws[k * D1 + g * 8];
      float4 wa = wr[0], wb = wr[1];
      acc[0] = fmaf(x0, wa.x, acc[0]);
      acc[1] = fmaf(x0, wa.y, acc[1]);
      acc[2] = fmaf(x0, wa.z, acc[2]);
      acc[3] = fmaf(x0, wa.w, acc[3]);
      acc[4] = fmaf(x0, wb.x, acc[4]);
      acc[5] = fmaf(x0, wb.y, acc[5]);
      acc[6] = fmaf(x0, wb.z, acc[6]);
      acc[7] = fmaf(x0, wb.w, acc[7]);
    }
    int n0 = base + nl;
    if (n0 < NN) {
      float s = 0.f, d = 0.f;
      uint4 pk;
      pk.x = (unsigned)f2bf(acc[0]) | ((unsigned)f2bf(acc[1]) << 16);
      pk.y = (unsigned)f2bf(acc[2]) | ((unsigned)f2bf(acc[3]) << 16);
      pk.z = (unsigned)f2bf(acc[4]) | ((unsigned)f2bf(acc[5]) << 16);
      pk.w = (unsigned)f2bf(acc[6]) | ((unsigned)f2bf(acc[7]) << 16);
      *(uint4*)(void*)(h + (size_t)n0 * D1 + g * 8) = pk;
      #pragma unroll
      for (int c = 0; c < 8; ++c) {
        s = fmaf(acc[c], aw_s[g * 8 + c], s);
        d = fmaf(acc[c], aw_d[g * 8 + c], d);
      }
      als[n0 * H1N + g] = s * LOG2E;
      ald[n0 * H1N + g] = d * LOG2E;
    }
  }
}

// ---- pass B: bucket_base computed in-block; hist -> scan -> placement ----
__global__ __launch_bounds__(256) void k_passB(const int* __restrict__ bcnt,
                       const unsigned int* __restrict__ subbuf,
                       int* __restrict__ row_start, int* __restrict__ csr) {
  __shared__ int hist[BNODES];
  __shared__ int ps[256];
  __shared__ int cur[BNODES];
  __shared__ int bbs;
  int b = blockIdx.x, t = threadIdx.x;
  int d0 = b << BSH;
  int nloc = min(BNODES, NN - d0);
  int tot = 0;
  if (t < NBUC) {
    int dd = t << BSH;
    tot = min(BNODES, NN - dd) + min(bcnt[t], BCAP);
  }
  ps[t] = tot;
  __syncthreads();
  for (int s = 1; s < 256; s <<= 1) {
    int xv = (t >= s) ? ps[t - s] : 0;
    __syncthreads();
    ps[t] += xv;
    __syncthreads();
  }
  if (t == 0) bbs = (b == 0) ? 0 : ps[b - 1];
  if (b == 0 && t == 0) row_start[NN] = ps[NBUC - 1];
  __syncthreads();
  int bucket_base = bbs;
  hist[t] = 0; hist[t + 256] = 0;
  __syncthreads();
  int cnt = min(bcnt[b], BCAP);
  const unsigned int* sb = subbuf + (size_t)b * BCAP;
  for (int i = t; i < cnt; i += 256)
    atomicAdd(&hist[sb[i] & (BNODES - 1)], 1);
  __syncthreads();
  int j0 = 2 * t, j1 = 2 * t + 1;
  int s0 = (j0 < nloc) ? hist[j0] + 1 : 0;
  int s1 = (j1 < nloc) ? hist[j1] + 1 : 0;
  int pairsum = s0 + s1;
  ps[t] = pairsum;
  __syncthreads();
  for (int s = 1; s < 256; s <<= 1) {
    int x = (t >= s) ? ps[t - s] : 0;
    __syncthreads();
    ps[t] += x;
    __syncthreads();
  }
  int excl = ps[t] - pairsum + bucket_base;
  if (j0 < nloc) {
    row_start[d0 + j0] = excl;
    csr[excl] = d0 + j0;
    cur[j0] = excl + 1;
  }
  if (j1 < nloc) {
    int rs = excl + s0;
    row_start[d0 + j1] = rs;
    csr[rs] = d0 + j1;
    cur[j1] = rs + 1;
  }
  __syncthreads();
  for (int i = t; i < cnt; i += 256) {
    unsigned u = sb[i];
    int pos = atomicAdd(&cur[u & (BNODES - 1)], 1);
    csr[pos] = (int)(u >> BSH);
  }
}

// ---- layer 1 aggregate + FUSED layer 2 linear ----------------------------
// 2 nodes/wave (independent 32-lane halves). After the gather loop, the
// half's x1 row (64 ch) goes to LDS; then h2 = x1@W2 (W2 bf16-packed in
// LDS), logits via 5-step shfl_xor within the half. k_lin2 eliminated.
__global__ __launch_bounds__(256) void k_node1f(
    const int* __restrict__ row_start, const int* __restrict__ csr,
    const unsigned short* __restrict__ h, const float* __restrict__ als,
    const float* __restrict__ ald, const float* __restrict__ b,
    const float* __restrict__ W2, const float* __restrict__ aw_s2,
    const float* __restrict__ aw_d2, unsigned int* __restrict__ h2_32,
    float* __restrict__ als2, float* __restrict__ ald2) {
  __shared__ float pl[4][2][32 * 9];       // 9KB
  __shared__ unsigned ws2p[D1 * 32];       // 8KB: [k][q] = bf16 cols {2q,2q+1}
  __shared__ float x1r[4][2][D1];          // 2KB
  int t = threadIdx.x;
  // stage W2 packed (zero-pad cols >= 40)
  for (int i = t; i < D1 * 32; i += 256) {
    int k = i >> 5, q = i & 31;
    int c0 = 2 * q, c1 = 2 * q + 1;
    unsigned lo = (c0 < NC) ? (unsigned)f2bf(W2[k * NC + c0]) : 0u;
    unsigned hi = (c1 < NC) ? (unsigned)f2bf(W2[k * NC + c1]) : 0u;
    ws2p[i] = lo | (hi << 16);
  }
  __syncthreads();
  int wid = t >> 6, half = (t >> 5) & 1, c2 = t & 31;
  int n = blockIdx.x * 8 + wid * 2 + half;          // NN % 8 == 0
  float* pw = pl[wid][half];
  float* xr = x1r[wid][half];
  const unsigned int* h32 = (const unsigned int*)h;
  int r0 = row_start[n], r1 = row_start[n + 1];
  int hd = c2 >> 2;
  const float4* adp = (const float4*)(ald + (size_t)n * H1N);
  float4 ad0 = adp[0], ad1 = adp[1];
  float S = 0.f;
  float alo0 = 0.f, ahi0 = 0.f, alo1 = 0.f, ahi1 = 0.f;
  float alo2 = 0.f, ahi2 = 0.f, alo3 = 0.f, ahi3 = 0.f;
  for (int kb = r0; kb < r1; kb += 32) {
    int cnt = min(32, r1 - kb);
    if (c2 < cnt) {
      int sk = csr[kb + c2];
      const float4* ap = (const float4*)(als + (size_t)sk * H1N);
      float4 a0 = ap[0], a1 = ap[1];
      pw[c2 * 9 + 0] = exp2fast(leakyf(a0.x + ad0.x));
      pw[c2 * 9 + 1] = exp2fast(leakyf(a0.y + ad0.y));
      pw[c2 * 9 + 2] = exp2fast(leakyf(a0.z + ad0.z));
      pw[c2 * 9 + 3] = exp2fast(leakyf(a0.w + ad0.w));
      pw[c2 * 9 + 4] = exp2fast(leakyf(a1.x + ad1.x));
      pw[c2 * 9 + 5] = exp2fast(leakyf(a1.y + ad1.y));
      pw[c2 * 9 + 6] = exp2fast(leakyf(a1.z + ad1.z));
      pw[c2 * 9 + 7] = exp2fast(leakyf(a1.w + ad1.w));
      pw[c2 * 9 + 8] = __int_as_float(sk);
    }
    asm volatile("s_waitcnt lgkmcnt(0)" ::: "memory");   // wave-internal LDS RAW
    int j = 0;
    for (; j + 4 <= cnt; j += 4) {
      int s0 = __float_as_int(pw[(j + 0) * 9 + 8]);
      int s1 = __float_as_int(pw[(j + 1) * 9 + 8]);
      int s2 = __float_as_int(pw[(j + 2) * 9 + 8]);
      int s3 = __float_as_int(pw[(j + 3) * 9 + 8]);
      float p0 = pw[(j + 0) * 9 + hd], p1 = pw[(j + 1) * 9 + hd];
      float p2 = pw[(j + 2) * 9 + hd], p3 = pw[(j + 3) * 9 + hd];
      unsigned u0 = h32[(unsigned)s0 * 32 + c2];
      unsigned u1 = h32[(unsigned)s1 * 32 + c2];
      unsigned u2 = h32[(unsigned)s2 * 32 + c2];
      unsigned u3 = h32[(unsigned)s3 * 32 + c2];
      alo0 = fmaf(p0, bflo(u0), alo0); ahi0 = fmaf(p0, bfhi(u0), ahi0);
      alo1 = fmaf(p1, bflo(u1), alo1); ahi1 = fmaf(p1, bfhi(u1), ahi1);
      alo2 = fmaf(p2, bflo(u2), alo2); ahi2 = fmaf(p2, bfhi(u2), ahi2);
      alo3 = fmaf(p3, bflo(u3), alo3); ahi3 = fmaf(p3, bfhi(u3), ahi3);
      S += (p0 + p1) + (p2 + p3);
    }
    for (; j < cnt; ++j) {
      int s0 = __float_as_int(pw[j * 9 + 8]);
      float p0 = pw[j * 9 + hd];
      unsigned u0 = h32[(unsigned)s0 * 32 + c2];
      alo0 = fmaf(p0, bflo(u0), alo0); ahi0 = fmaf(p0, bfhi(u0), ahi0);
      S += p0;
    }
  }
  float alo = (alo0 + alo1) + (alo2 + alo3);
  float ahi = (ahi0 + ahi1) + (ahi2 + ahi3);
  float inv = 1.0f / (S + 1e-16f);
  float ox = eluf(alo * inv + b[2 * c2 + 0]);
  float oy = eluf(ahi * inv + b[2 * c2 + 1]);
  // ---- fused lin2: x1 row -> LDS, h2 = x1 @ W2 ---------------------------
  xr[2 * c2 + 0] = ox;
  xr[2 * c2 + 1] = oy;
  asm volatile("s_waitcnt lgkmcnt(0)" ::: "memory");     // wave-internal LDS RAW
  float a20 = 0.f, a21 = 0.f;
  #pragma unroll 4
  for (int k = 0; k < D1; ++k) {
    float xv = xr[k];                                    // broadcast
    unsigned wp = ws2p[k * 32 + c2];                     // bank-perfect
    a20 = fmaf(xv, bflo(wp), a20);
    a21 = fmaf(xv, bfhi(wp), a21);
  }
  float aws0 = (c2 < 20) ? aw_s2[2 * c2] : 0.f;
  float aws1 = (c2 < 20) ? aw_s2[2 * c2 + 1] : 0.f;
  float awd0 = (c2 < 20) ? aw_d2[2 * c2] : 0.f;
  float awd1 = (c2 < 20) ? aw_d2[2 * c2 + 1] : 0.f;
  float s2l = a20 * aws0 + a21 * aws1;
  float d2l = a20 * awd0 + a21 * awd1;
  s2l += __shfl_xor(s2l, 1);  d2l += __shfl_xor(d2l, 1);
  s2l += __shfl_xor(s2l, 2);  d2l += __shfl_xor(d2l, 2);
  s2l += __shfl_xor(s2l, 4);  d2l += __shfl_xor(d2l, 4);
  s2l += __shfl_xor(s2l, 8);  d2l += __shfl_xor(d2l, 8);
  s2l += __shfl_xor(s2l, 16); d2l += __shfl_xor(d2l, 16);
  if (c2 < 20)
    h2_32[(size_t)n * 20 + c2] = (unsigned)f2bf(a20) | ((unsigned)f2bf(a21) << 16);
  if (c2 == 0) { als2[n] = s2l * LOG2E; ald2[n] = d2l * LOG2E; }
}

// ---- layer 2 aggregate: 3 nodes/wave (20 lanes each) ---------------------
__global__ void k_node2(const int* __restrict__ row_start, const int* __restrict__ csr,
                        const unsigned int* __restrict__ h32, const float* __restrict__ als,
                        const float* __restrict__ ald, const float* __restrict__ b,
                        float* __restrict__ out) {
  __shared__ float pl[4][3][20 * 2];
  int wid = threadIdx.x >> 6, lane = threadIdx.x & 63;
  int g = lane / 20, q = lane - g * 20;
  int gg = g < 3 ? g : 2;
  int n = blockIdx.x * 12 + wid * 3 + gg;
  bool live = (g < 3) && (n < NN);
  if (n >= NN) n = NN - 1;
  float* pw = pl[wid][gg];
  int r0 = row_start[n], r1 = row_start[n + 1];
  float aldn = ald[n];
  float S = 0.f;
  float alo0 = 0.f, ahi0 = 0.f, alo1 = 0.f, ahi1 = 0.f;
  float alo2 = 0.f, ahi2 = 0.f, alo3 = 0.f, ahi3 = 0.f;
  for (int kb = r0; kb < r1; kb += 20) {
    int cnt = min(20, r1 - kb);
    if (q < cnt && g < 3) {
      int sk = csr[kb + q];
      pw[q * 2 + 0] = exp2fast(leakyf(als[sk] + aldn));
      pw[q * 2 + 1] = __int_as_float(sk);
    }
    asm volatile("s_waitcnt lgkmcnt(0)" ::: "memory");
    int j = 0;
    for (; j + 4 <= cnt; j += 4) {
      int s0 = __float_as_int(pw[(j + 0) * 2 + 1]);
      int s1 = __float_as_int(pw[(j + 1) * 2 + 1]);
      int s2 = __float_as_int(pw[(j + 2) * 2 + 1]);
      int s3 = __float_as_int(pw[(j + 3) * 2 + 1]);
      float p0 = pw[(j + 0) * 2], p1 = pw[(j + 1) * 2];
      float p2 = pw[(j + 2) * 2], p3 = pw[(j + 3) * 2];
      unsigned u0 = h32[(unsigned)s0 * 20 + q];
      unsigned u1 = h32[(unsigned)s1 * 20 + q];
      unsigned u2 = h32[(unsigned)s2 * 20 + q];
      unsigned u3 = h32[(unsigned)s3 * 20 + q];
      alo0 = fmaf(p0, bflo(u0), alo0); ahi0 = fmaf(p0, bfhi(u0), ahi0);
      alo1 = fmaf(p1, bflo(u1), alo1); ahi1 = fmaf(p1, bfhi(u1), ahi1);
      alo2 = fmaf(p2, bflo(u2), alo2); ahi2 = fmaf(p2, bfhi(u2), ahi2);
      alo3 = fmaf(p3, bflo(u3), alo3); ahi3 = fmaf(p3, bfhi(u3), ahi3);
      S += (p0 + p1) + (p2 + p3);
    }
    for (; j < cnt; ++j) {
      int s0 = __float_as_int(pw[j * 2 + 1]);
      float p0 = pw[j * 2];
      unsigned u0 = h32[(unsigned)s0 * 20 + q];
      alo0 = fmaf(p0, bflo(u0), alo0); ahi0 = fmaf(p0, bfhi(u0), ahi0);
      S += p0;
    }
  }
  float alo = (alo0 + alo1) + (alo2 + alo3);
  float ahi = (ahi0 + ahi1) + (ahi2 + ahi3);
  if (live) {
    float inv = 1.0f / (S + 1e-16f);
    float2 o;
    o.x = eluf(alo * inv + b[2 * q + 0]);
    o.y = eluf(ahi * inv + b[2 * q + 1]);
    ((float2*)out)[(size_t)n * 20 + q] = o;
  }
}

extern "C" void kernel_launch(void* const* d_in, const int* in_sizes, int n_in,
                              void* d_out, int out_size, void* d_ws, size_t ws_size,
                              hipStream_t stream) {
  const float* x    = (const float*)d_in[0];
  const void*  ei   = d_in[1];
  const float* W1   = (const float*)d_in[3];
  const float* as1w = (const float*)d_in[4];
  const float* ad1w = (const float*)d_in[5];
  const float* b1   = (const float*)d_in[6];
  const float* W2   = (const float*)d_in[7];
  const float* as2w = (const float*)d_in[8];
  const float* ad2w = (const float*)d_in[9];
  const float* b2   = (const float*)d_in[10];
  float* out = (float*)d_out;

  char* w = (char*)d_ws;
  size_t off = 0;
  auto carve = [&](size_t bytes) -> void* {
    void* r = w + off;
    off += (bytes + 255) & ~(size_t)255;
    return r;
  };
  int*            flag      = (int*)carve(256);
  int*            bcnt      = (int*)carve((size_t)NBUC * 4);
  unsigned int*   subbuf    = (unsigned int*)carve((size_t)NBUC * BCAP * 4);
  int*            row_start = (int*)carve((size_t)(NN + 1) * 4);
  int*            csr       = (int*)carve((size_t)NETOT * 4);
  unsigned short* h1        = (unsigned short*)carve((size_t)NN * D1 * 2);  // bf16
  float*          als1      = (float*)carve((size_t)NN * H1N * 4);
  float*          ald1      = (float*)carve((size_t)NN * H1N * 4);
  unsigned int*   h2_32     = (unsigned int*)carve((size_t)NN * 20 * 4);    // bf16-packed [N,40]
  float*          als2      = (float*)carve((size_t)NN * 4);
  float*          ald2      = (float*)carve((size_t)NN * 4);

  // detect dtype + zero bucket counters (one dispatch)
  k_detect<<<1, 256, 0, stream>>>((const long long*)ei, flag, bcnt);

  // fused: passA bucket-sort + lin1 GEMM (independent work, one dispatch)
  k_fusedA<<<NBLKA + LB, 512, 0, stream>>>(ei, flag, subbuf, bcnt,
                                           x, W1, as1w, ad1w, h1, als1, ald1);

  // CSR finalize (bucket_base computed in-block)
  k_passB<<<NBUC, 256, 0, stream>>>(bcnt, subbuf, row_start, csr);

  // layer 1 aggregate + fused layer 2 linear
  k_node1f<<<NN / 8, 256, 0, stream>>>(row_start, csr, h1, als1, ald1, b1,
                                       W2, as2w, ad2w, h2_32, als2, ald2);

  // layer 2 aggregate
  k_node2<<<(NN + 11) / 12, 256, 0, stream>>>(row_start, csr, h2_32, als2, ald2, b2, out);
}

// Round 19
// 203.004 us; speedup vs baseline: 1.0660x; 1.0660x over previous
//
#include <hip/hip_runtime.h>
#include <math.h>

#define NN 100000
#define NE 1600000
#define NETOT (NE + NN)
#define FIN 128
#define H1N 8
#define D1 64
#define NC 40
#define LNT 64                        // nodes per tile in lin kernels
#define LOG2E 1.44269504088896f

#define BSH 9                         // 512 dst nodes per bucket
#define BNODES 512
#define NBUC ((NN + BNODES - 1) / BNODES)   // 196
#define EPB 4096                      // edges per passA block
#define NBLKA ((NE + EPB - 1) / EPB)  // 391
#define BCAP 9216                     // per-bucket edge capacity (mean 8192, +11 sigma)
#define LB ((NN + LNT - 1) / LNT)     // 1563

__device__ __forceinline__ float leakyf(float x) { return x >= 0.0f ? x : 0.2f * x; }
__device__ __forceinline__ float eluf(float x)   { return x > 0.0f ? x : expm1f(x); }
__device__ __forceinline__ float exp2fast(float x) { return __builtin_amdgcn_exp2f(x); }

// bf16 helpers
__device__ __forceinline__ unsigned short f2bf(float f) {
  unsigned u = __float_as_uint(f);
  u += 0x7fffu + ((u >> 16) & 1u);
  return (unsigned short)(u >> 16);
}
__device__ __forceinline__ float bflo(unsigned u) { return __uint_as_float(u << 16); }
__device__ __forceinline__ float bfhi(unsigned u) { return __uint_as_float(u & 0xffff0000u); }

// ---- detect edge dtype + zero bucket counters ----------------------------
__global__ void k_detect(const long long* __restrict__ ei, int* __restrict__ flag,
                         int* __restrict__ bcnt) {
  int t = threadIdx.x;
  if (t < NBUC) bcnt[t] = 0;
  if (t == 0) {
    int is64 = 1;
    for (int i = 0; i < 16; ++i) {
      long long v = ei[i];
      if (v < 0 || v >= NN) is64 = 0;
    }
    *flag = is64;
  }
}

// ---- fused: blocks [0,NBLKA) = passA bucket-sort; rest = lin1 GEMM -------
// lin1 = R12 formulation (proven local optimum): fp32 swizzled x-tile,
// thread = (head g, node nl), per k: 2 ds_read_b128 (W) + 1 ds_read_b32 (x).
#define XS1(node, k) xs[(node) * FIN + ((k) ^ ((node) & 31))]
__global__ __launch_bounds__(512) void k_fusedA(
    const void* __restrict__ ei, const int* __restrict__ flag,
    unsigned int* __restrict__ subbuf, int* __restrict__ bcnt,
    const float* __restrict__ x, const float* __restrict__ W,
    const float* __restrict__ aw_s, const float* __restrict__ aw_d,
    unsigned short* __restrict__ h, float* __restrict__ als,
    float* __restrict__ ald) {
  __shared__ __align__(16) char smem[65536];
  int t = threadIdx.x;
  if (blockIdx.x < NBLKA) {
    // ---------------- passA: block-local LDS counting sort ----------------
    unsigned int*   pay    = (unsigned int*)smem;            // 16KB
    unsigned int*   spay   = pay + EPB;                      // 16KB
    unsigned short* bk     = (unsigned short*)(spay + EPB);  // 8KB
    unsigned short* sbk    = bk + EPB;                       // 8KB
    int*            hist   = (int*)(sbk + EPB);              // 1KB
    int*            lstart = hist + 256;                     // 1KB
    int*            cur    = lstart + 256;                   // 1KB
    int*            gbase  = cur + 256;                      // 1KB
    int e0 = blockIdx.x * EPB;
    int cnt = min(EPB, NE - e0);
    if (t < 256) hist[t] = 0;
    __syncthreads();
    bool f64 = (*flag) != 0;
    for (int i = t; i < cnt; i += 512) {
      int s, d;
      if (f64) {
        const long long* p = (const long long*)ei;
        s = (int)p[e0 + i]; d = (int)p[NE + e0 + i];
      } else {
        const int* p = (const int*)ei;
        s = p[e0 + i]; d = p[NE + e0 + i];
      }
      int b = d >> BSH;
      pay[i] = ((unsigned)s << BSH) | (unsigned)(d & (BNODES - 1));
      bk[i] = (unsigned short)b;
      atomicAdd(&hist[b], 1);
    }
    __syncthreads();
    int v = 0;
    if (t < 256) { v = hist[t]; lstart[t] = v; }
    __syncthreads();
    for (int st = 1; st < 256; st <<= 1) {
      int xv = (t < 256 && t >= st) ? lstart[t - st] : 0;
      __syncthreads();
      if (t < 256) lstart[t] += xv;
      __syncthreads();
    }
    int excl = 0;
    if (t < 256) excl = lstart[t] - v;
    __syncthreads();
    if (t < 256) {
      lstart[t] = excl;
      cur[t] = excl;
      gbase[t] = (v > 0) ? atomicAdd(&bcnt[t], v) : 0;
    }
    __syncthreads();
    for (int i = t; i < cnt; i += 512) {
      int b = bk[i];
      int pos = atomicAdd(&cur[b], 1);
      spay[pos] = pay[i];
      sbk[pos] = (unsigned short)b;
    }
    __syncthreads();
    for (int i = t; i < cnt; i += 512) {
      int b = sbk[i];
      int o = gbase[b] + (i - lstart[b]);
      if (o < BCAP) subbuf[(size_t)b * BCAP + o] = spay[i];
    }
  } else {
    // ---------------- lin1: LDS-tiled GEMM, 1 node x 8 cols / thread ------
    float* ws = (float*)smem;            // 32KB [128][64]
    float* xs = ws + FIN * D1;           // 32KB [64][128] swizzled
    int base = (blockIdx.x - NBLKA) * LNT;
    for (int i = t; i < FIN * D1; i += 512) ws[i] = W[i];
    for (int i = t; i < LNT * FIN; i += 512) {
      int node = i >> 7, k = i & 127;
      int gn = base + node;
      if (gn >= NN) gn = NN - 1;
      XS1(node, k) = x[(size_t)gn * FIN + k];
    }
    __syncthreads();
    int g = t & 7, nl = t >> 3;          // head g, node nl in 0..63
    float acc[8] = {0, 0, 0, 0, 0, 0, 0, 0};
    #pragma unroll 4
    for (int k = 0; k < FIN; ++k) {
      float x0 = XS1(nl, k);
      const float4* wr = (const float4*)&ws[k * D1 + g * 8];
      float4 wa = wr[0], wb = wr[1];
      acc[0] = fmaf(x0, wa.x, acc[0]);
      acc[1] = fmaf(x0, wa.y, acc[1]);
      acc[2] = fmaf(x0, wa.z, acc[2]);
      acc[3] = fmaf(x0, wa.w, acc[3]);
      acc[4] = fmaf(x0, wb.x, acc[4]);
      acc[5] = fmaf(x0, wb.y, acc[5]);
      acc[6] = fmaf(x0, wb.z, acc[6]);
      acc[7] = fmaf(x0, wb.w, acc[7]);
    }
    int n0 = base + nl;
    if (n0 < NN) {
      float s = 0.f, d = 0.f;
      uint4 pk;
      pk.x = (unsigned)f2bf(acc[0]) | ((unsigned)f2bf(acc[1]) << 16);
      pk.y = (unsigned)f2bf(acc[2]) | ((unsigned)f2bf(acc[3]) << 16);
      pk.z = (unsigned)f2bf(acc[4]) | ((unsigned)f2bf(acc[5]) << 16);
      pk.w = (unsigned)f2bf(acc[6]) | ((unsigned)f2bf(acc[7]) << 16);
      *(uint4*)(void*)(h + (size_t)n0 * D1 + g * 8) = pk;
      #pragma unroll
      for (int c = 0; c < 8; ++c) {
        s = fmaf(acc[c], aw_s[g * 8 + c], s);
        d = fmaf(acc[c], aw_d[g * 8 + c], d);
      }
      als[n0 * H1N + g] = s * LOG2E;
      ald[n0 * H1N + g] = d * LOG2E;
    }
  }
}

// ---- pass B: bucket_base computed in-block; hist -> scan -> placement ----
__global__ __launch_bounds__(256) void k_passB(const int* __restrict__ bcnt,
                       const unsigned int* __restrict__ subbuf,
                       int* __restrict__ row_start, int* __restrict__ csr) {
  __shared__ int hist[BNODES];
  __shared__ int ps[256];
  __shared__ int cur[BNODES];
  __shared__ int bbs;
  int b = blockIdx.x, t = threadIdx.x;
  int d0 = b << BSH;
  int nloc = min(BNODES, NN - d0);
  int tot = 0;
  if (t < NBUC) {
    int dd = t << BSH;
    tot = min(BNODES, NN - dd) + min(bcnt[t], BCAP);
  }
  ps[t] = tot;
  __syncthreads();
  for (int s = 1; s < 256; s <<= 1) {
    int xv = (t >= s) ? ps[t - s] : 0;
    __syncthreads();
    ps[t] += xv;
    __syncthreads();
  }
  if (t == 0) bbs = (b == 0) ? 0 : ps[b - 1];
  if (b == 0 && t == 0) row_start[NN] = ps[NBUC - 1];
  __syncthreads();
  int bucket_base = bbs;
  hist[t] = 0; hist[t + 256] = 0;
  __syncthreads();
  int cnt = min(bcnt[b], BCAP);
  const unsigned int* sb = subbuf + (size_t)b * BCAP;
  for (int i = t; i < cnt; i += 256)
    atomicAdd(&hist[sb[i] & (BNODES - 1)], 1);
  __syncthreads();
  int j0 = 2 * t, j1 = 2 * t + 1;
  int s0 = (j0 < nloc) ? hist[j0] + 1 : 0;
  int s1 = (j1 < nloc) ? hist[j1] + 1 : 0;
  int pairsum = s0 + s1;
  ps[t] = pairsum;
  __syncthreads();
  for (int s = 1; s < 256; s <<= 1) {
    int x = (t >= s) ? ps[t - s] : 0;
    __syncthreads();
    ps[t] += x;
    __syncthreads();
  }
  int excl = ps[t] - pairsum + bucket_base;
  if (j0 < nloc) {
    row_start[d0 + j0] = excl;
    csr[excl] = d0 + j0;
    cur[j0] = excl + 1;
  }
  if (j1 < nloc) {
    int rs = excl + s0;
    row_start[d0 + j1] = rs;
    csr[rs] = d0 + j1;
    cur[j1] = rs + 1;
  }
  __syncthreads();
  for (int i = t; i < cnt; i += 256) {
    unsigned u = sb[i];
    int pos = atomicAdd(&cur[u & (BNODES - 1)], 1);
    csr[pos] = (int)(u >> BSH);
  }
}

// ---- layer 2 linear: 512 threads, reads packed-bf16 x1; h2 bf16 ----------
#define XS2(node, k) xs[(node) * D1 + ((k) ^ ((node) & 31))]
__global__ __launch_bounds__(512) void k_lin2(
    const unsigned int* __restrict__ x1bf, const float* __restrict__ W,
    const float* __restrict__ aw_s, const float* __restrict__ aw_d,
    unsigned short* __restrict__ h, float* __restrict__ als,
    float* __restrict__ ald) {
  __shared__ float ws[D1 * D1];        // 16KB (zero-padded [64][64])
  __shared__ float xs[LNT * D1];       // 16KB
  int t = threadIdx.x;
  int base = blockIdx.x * LNT;
  for (int i = t; i < D1 * D1; i += 512) {
    int k = i >> 6, c = i & 63;
    ws[i] = (c < NC) ? W[k * NC + c] : 0.f;
  }
  for (int i = t; i < LNT * 32; i += 512) {
    int node = i >> 5, kd = i & 31;
    int gn = base + node;
    if (gn >= NN) gn = NN - 1;
    unsigned u = x1bf[(size_t)gn * 32 + kd];
    XS2(node, 2 * kd)     = bflo(u);
    XS2(node, 2 * kd + 1) = bfhi(u);
  }
  __syncthreads();
  int g = t & 7, nl = t >> 3;
  float acc[8] = {0, 0, 0, 0, 0, 0, 0, 0};
  #pragma unroll 4
  for (int k = 0; k < D1; ++k) {
    float x0 = XS2(nl, k);
    const float4* wr = (const float4*)&ws[k * D1 + g * 8];
    float4 wa = wr[0], wb = wr[1];
    acc[0] = fmaf(x0, wa.x, acc[0]);
    acc[1] = fmaf(x0, wa.y, acc[1]);
    acc[2] = fmaf(x0, wa.z, acc[2]);
    acc[3] = fmaf(x0, wa.w, acc[3]);
    acc[4] = fmaf(x0, wb.x, acc[4]);
    acc[5] = fmaf(x0, wb.y, acc[5]);
    acc[6] = fmaf(x0, wb.z, acc[6]);
    acc[7] = fmaf(x0, wb.w, acc[7]);
  }
  int n0 = base + nl;
  float s = 0.f, d = 0.f;
  #pragma unroll
  for (int c = 0; c < 8; ++c) {
    int col = g * 8 + c;
    float aws = (col < NC) ? aw_s[col] : 0.f;
    float awd = (col < NC) ? aw_d[col] : 0.f;
    s = fmaf(acc[c], aws, s);
    d = fmaf(acc[c], awd, d);
  }
  s += __shfl_xor(s, 1); d += __shfl_xor(d, 1);
  s += __shfl_xor(s, 2); d += __shfl_xor(d, 2);
  s += __shfl_xor(s, 4); d += __shfl_xor(d, 4);
  if (n0 < NN) {
    if (g < 5) {
      #pragma unroll
      for (int c = 0; c < 8; ++c) h[(size_t)n0 * NC + g * 8 + c] = f2bf(acc[c]);
    }
    if (g == 0) { als[n0] = s * LOG2E; ald[n0] = d * LOG2E; }
  }
}

// ---- layer 1 aggregate: 2 nodes/wave, independent 32-lane halves ---------
__global__ void k_node1(const int* __restrict__ row_start, const int* __restrict__ csr,
                        const unsigned short* __restrict__ h, const float* __restrict__ als,
                        const float* __restrict__ ald, const float* __restrict__ b,
                        unsigned int* __restrict__ x1bf) {
  __shared__ float pl[4][2][32 * 9];
  int wid = threadIdx.x >> 6, half = (threadIdx.x >> 5) & 1, c2 = threadIdx.x & 31;
  int n = blockIdx.x * 8 + wid * 2 + half;          // NN % 8 == 0
  float* pw = pl[wid][half];
  const unsigned int* h32 = (const unsigned int*)h;
  int r0 = row_start[n], r1 = row_start[n + 1];
  int hd = c2 >> 2;
  const float4* adp = (const float4*)(ald + (size_t)n * H1N);
  float4 ad0 = adp[0], ad1 = adp[1];
  float S = 0.f;
  float alo0 = 0.f, ahi0 = 0.f, alo1 = 0.f, ahi1 = 0.f;
  float alo2 = 0.f, ahi2 = 0.f, alo3 = 0.f, ahi3 = 0.f;
  for (int kb = r0; kb < r1; kb += 32) {
    int cnt = min(32, r1 - kb);
    if (c2 < cnt) {
      int sk = csr[kb + c2];
      const float4* ap = (const float4*)(als + (size_t)sk * H1N);
      float4 a0 = ap[0], a1 = ap[1];
      pw[c2 * 9 + 0] = exp2fast(leakyf(a0.x + ad0.x));
      pw[c2 * 9 + 1] = exp2fast(leakyf(a0.y + ad0.y));
      pw[c2 * 9 + 2] = exp2fast(leakyf(a0.z + ad0.z));
      pw[c2 * 9 + 3] = exp2fast(leakyf(a0.w + ad0.w));
      pw[c2 * 9 + 4] = exp2fast(leakyf(a1.x + ad1.x));
      pw[c2 * 9 + 5] = exp2fast(leakyf(a1.y + ad1.y));
      pw[c2 * 9 + 6] = exp2fast(leakyf(a1.z + ad1.z));
      pw[c2 * 9 + 7] = exp2fast(leakyf(a1.w + ad1.w));
      pw[c2 * 9 + 8] = __int_as_float(sk);
    }
    asm volatile("s_waitcnt lgkmcnt(0)" ::: "memory");   // wave-internal LDS RAW
    int j = 0;
    for (; j + 4 <= cnt; j += 4) {
      int s0 = __float_as_int(pw[(j + 0) * 9 + 8]);
      int s1 = __float_as_int(pw[(j + 1) * 9 + 8]);
      int s2 = __float_as_int(pw[(j + 2) * 9 + 8]);
      int s3 = __float_as_int(pw[(j + 3) * 9 + 8]);
      float p0 = pw[(j + 0) * 9 + hd], p1 = pw[(j + 1) * 9 + hd];
      float p2 = pw[(j + 2) * 9 + hd], p3 = pw[(j + 3) * 9 + hd];
      unsigned u0 = h32[(unsigned)s0 * 32 + c2];
      unsigned u1 = h32[(unsigned)s1 * 32 + c2];
      unsigned u2 = h32[(unsigned)s2 * 32 + c2];
      unsigned u3 = h32[(unsigned)s3 * 32 + c2];
      alo0 = fmaf(p0, bflo(u0), alo0); ahi0 = fmaf(p0, bfhi(u0), ahi0);
      alo1 = fmaf(p1, bflo(u1), alo1); ahi1 = fmaf(p1, bfhi(u1), ahi1);
      alo2 = fmaf(p2, bflo(u2), alo2); ahi2 = fmaf(p2, bfhi(u2), ahi2);
      alo3 = fmaf(p3, bflo(u3), alo3); ahi3 = fmaf(p3, bfhi(u3), ahi3);
      S += (p0 + p1) + (p2 + p3);
    }
    for (; j < cnt; ++j) {
      int s0 = __float_as_int(pw[j * 9 + 8]);
      float p0 = pw[j * 9 + hd];
      unsigned u0 = h32[(unsigned)s0 * 32 + c2];
      alo0 = fmaf(p0, bflo(u0), alo0); ahi0 = fmaf(p0, bfhi(u0), ahi0);
      S += p0;
    }
  }
  float alo = (alo0 + alo1) + (alo2 + alo3);
  float ahi = (ahi0 + ahi1) + (ahi2 + ahi3);
  float inv = 1.0f / (S + 1e-16f);
  float ox = eluf(alo * inv + b[2 * c2 + 0]);
  float oy = eluf(ahi * inv + b[2 * c2 + 1]);
  x1bf[(size_t)n * 32 + c2] = (unsigned)f2bf(ox) | ((unsigned)f2bf(oy) << 16);
}

// ---- layer 2 aggregate: 3 nodes/wave (20 lanes each) ---------------------
__global__ void k_node2(const int* __restrict__ row_start, const int* __restrict__ csr,
                        const unsigned short* __restrict__ h, const float* __restrict__ als,
                        const float* __restrict__ ald, const float* __restrict__ b,
                        float* __restrict__ out) {
  __shared__ float pl[4][3][20 * 2];
  int wid = threadIdx.x >> 6, lane = threadIdx.x & 63;
  int g = lane / 20, q = lane - g * 20;
  int gg = g < 3 ? g : 2;
  int n = blockIdx.x * 12 + wid * 3 + gg;
  bool live = (g < 3) && (n < NN);
  if (n >= NN) n = NN - 1;
  float* pw = pl[wid][gg];
  const unsigned int* h32 = (const unsigned int*)h;
  int r0 = row_start[n], r1 = row_start[n + 1];
  float aldn = ald[n];
  float S = 0.f;
  float alo0 = 0.f, ahi0 = 0.f, alo1 = 0.f, ahi1 = 0.f;
  float alo2 = 0.f, ahi2 = 0.f, alo3 = 0.f, ahi3 = 0.f;
  for (int kb = r0; kb < r1; kb += 20) {
    int cnt = min(20, r1 - kb);
    if (q < cnt && g < 3) {
      int sk = csr[kb + q];
      pw[q * 2 + 0] = exp2fast(leakyf(als[sk] + aldn));
      pw[q * 2 + 1] = __int_as_float(sk);
    }
    asm volatile("s_waitcnt lgkmcnt(0)" ::: "memory");
    int j = 0;
    for (; j + 4 <= cnt; j += 4) {
      int s0 = __float_as_int(pw[(j + 0) * 2 + 1]);
      int s1 = __float_as_int(pw[(j + 1) * 2 + 1]);
      int s2 = __float_as_int(pw[(j + 2) * 2 + 1]);
      int s3 = __float_as_int(pw[(j + 3) * 2 + 1]);
      float p0 = pw[(j + 0) * 2], p1 = pw[(j + 1) * 2];
      float p2 = pw[(j + 2) * 2], p3 = pw[(j + 3) * 2];
      unsigned u0 = h32[(unsigned)s0 * 20 + q];
      unsigned u1 = h32[(unsigned)s1 * 20 + q];
      unsigned u2 = h32[(unsigned)s2 * 20 + q];
      unsigned u3 = h32[(unsigned)s3 * 20 + q];
      alo0 = fmaf(p0, bflo(u0), alo0); ahi0 = fmaf(p0, bfhi(u0), ahi0);
      alo1 = fmaf(p1, bflo(u1), alo1); ahi1 = fmaf(p1, bfhi(u1), ahi1);
      alo2 = fmaf(p2, bflo(u2), alo2); ahi2 = fmaf(p2, bfhi(u2), ahi2);
      alo3 = fmaf(p3, bflo(u3), alo3); ahi3 = fmaf(p3, bfhi(u3), ahi3);
      S += (p0 + p1) + (p2 + p3);
    }
    for (; j < cnt; ++j) {
      int s0 = __float_as_int(pw[j * 2 + 1]);
      float p0 = pw[j * 2];
      unsigned u0 = h32[(unsigned)s0 * 20 + q];
      alo0 = fmaf(p0, bflo(u0), alo0); ahi0 = fmaf(p0, bfhi(u0), ahi0);
      S += p0;
    }
  }
  float alo = (alo0 + alo1) + (alo2 + alo3);
  float ahi = (ahi0 + ahi1) + (ahi2 + ahi3);
  if (live) {
    float inv = 1.0f / (S + 1e-16f);
    float2 o;
    o.x = eluf(alo * inv + b[2 * q + 0]);
    o.y = eluf(ahi * inv + b[2 * q + 1]);
    ((float2*)out)[(size_t)n * 20 + q] = o;
  }
}

extern "C" void kernel_launch(void* const* d_in, const int* in_sizes, int n_in,
                              void* d_out, int out_size, void* d_ws, size_t ws_size,
                              hipStream_t stream) {
  const float* x    = (const float*)d_in[0];
  const void*  ei   = d_in[1];
  const float* W1   = (const float*)d_in[3];
  const float* as1w = (const float*)d_in[4];
  const float* ad1w = (const float*)d_in[5];
  const float* b1   = (const float*)d_in[6];
  const float* W2   = (const float*)d_in[7];
  const float* as2w = (const float*)d_in[8];
  const float* ad2w = (const float*)d_in[9];
  const float* b2   = (const float*)d_in[10];
  float* out = (float*)d_out;

  char* w = (char*)d_ws;
  size_t off = 0;
  auto carve = [&](size_t bytes) -> void* {
    void* r = w + off;
    off += (bytes + 255) & ~(size_t)255;
    return r;
  };
  int*            flag        = (int*)carve(256);
  int*            bcnt        = (int*)carve((size_t)NBUC * 4);
  unsigned int*   subbuf      = (unsigned int*)carve((size_t)NBUC * BCAP * 4);
  int*            row_start   = (int*)carve((size_t)(NN + 1) * 4);
  int*            csr         = (int*)carve((size_t)NETOT * 4);
  unsigned short* h1          = (unsigned short*)carve((size_t)NN * D1 * 2);  // bf16; reused as h2
  float*          als1        = (float*)carve((size_t)NN * H1N * 4);  // reused as als2
  float*          ald1        = (float*)carve((size_t)NN * H1N * 4);  // reused as ald2
  unsigned int*   x1bf        = (unsigned int*)carve((size_t)NN * 32 * 4);  // packed bf16 [N,32]
  unsigned short* h2 = h1; float* als2 = als1; float* ald2 = ald1;

  // detect dtype + zero bucket counters (one dispatch)
  k_detect<<<1, 256, 0, stream>>>((const long long*)ei, flag, bcnt);

  // fused: passA bucket-sort + lin1 GEMM (independent work, one dispatch)
  k_fusedA<<<NBLKA + LB, 512, 0, stream>>>(ei, flag, subbuf, bcnt,
                                           x, W1, as1w, ad1w, h1, als1, ald1);

  // CSR finalize (bucket_base computed in-block)
  k_passB<<<NBUC, 256, 0, stream>>>(bcnt, subbuf, row_start, csr);

  // layer 1 aggregate
  k_node1<<<NN / 8, 256, 0, stream>>>(row_start, csr, h1, als1, ald1, b1, x1bf);

  // layer 2
  k_lin2<<<LB, 512, 0, stream>>>(x1bf, W2, as2w, ad2w, h2, als2, ald2);
  k_node2<<<(NN + 11) / 12, 256, 0, stream>>>(row_start, csr, h2, als2, ald2, b2, out);
}